// Round 3
// baseline (1115.392 us; speedup 1.0000x reference)
//
#include <hip/hip_runtime.h>
#include <math.h>

#define B_ 16
#define T_ 12
#define N_ 1024
#define D_ 64
#define HS_ 16
#define HT_ 64
#define TT_ 192
#define BT_ 192

typedef _Float16 f16x2 __attribute__((ext_vector_type(2)));

__device__ __forceinline__ unsigned int pkrtz(float a, float b){
    auto r = __builtin_amdgcn_cvt_pkrtz(a, b);
    return __builtin_bit_cast(unsigned int, r);
}
__device__ __forceinline__ float fdot2u(unsigned int a, unsigned int b, float c){
    return __builtin_amdgcn_fdot2(__builtin_bit_cast(f16x2, a),
                                  __builtin_bit_cast(f16x2, b), c, false);
}
__device__ __forceinline__ float loF(unsigned int a){ f16x2 h = __builtin_bit_cast(f16x2, a); return (float)h.x; }
__device__ __forceinline__ float hiF(unsigned int a){ f16x2 h = __builtin_bit_cast(f16x2, a); return (float)h.y; }

__device__ __forceinline__ float lrelu_(float v){ return v > 0.f ? v : 0.01f*v; }
__device__ __forceinline__ float squash_sc(float sn){ return (sn/(1.f+sn))/(sqrtf(sn)+1e-8f); }

__device__ __forceinline__ float wredsum64(float v){
    #pragma unroll
    for (int mk = 1; mk < 64; mk <<= 1) v += __shfl_xor(v, mk, 64);
    return v;
}

// PT layout: f16 pair (n=2m, n=2m+1) of P[.][d], row d (stride 524 u32),
// column-quad mb stored at ((mb + (d>>3)) & 127)  -> uniform bank groups for b128.
__device__ __forceinline__ int ptq_idx(int d, int mb){
    return d*524 + 4*((mb + (d>>3)) & 127);
}

#define MEGA_LDS 155904
// PT:   [0, 134144)           64*524*4
// CLTP: [134144, 151552)      CL u32[16][256] / TP f32[4][16][68] / XST u32[8][256]
// VB:   [151552, 155904)      f32[16][68]

__global__ __launch_bounds__(512, 2) void k_mega(
        const float* __restrict__ x, const float* __restrict__ Wp,
        const float* __restrict__ bp, const float* __restrict__ teb,
        const float* __restrict__ adj,
        float* __restrict__ cout, float* __restrict__ sbuf){
    extern __shared__ char smem[];
    unsigned int* PT  = (unsigned int*)smem;
    unsigned int* CL  = (unsigned int*)(smem + 134144);
    float*        TP  = (float*)(smem + 134144);
    unsigned int* XST = (unsigned int*)(smem + 134144);
    float*        VB  = (float*)(smem + 151552);

    const int t  = threadIdx.x;
    const int bt = blockIdx.x;
    const int w  = t >> 6, l = t & 63;

    // ---- W rows (f16 packed) into regs: lane l holds W[l][2j],W[l][2j+1]
    unsigned int wpk[32];
    float bpd = bp[l];
    #pragma unroll
    for (int j = 0; j < 32; ++j){
        float2 w2 = *(const float2*)(Wp + l*64 + 2*j);
        wpk[j] = pkrtz(w2.x, w2.y);
    }

    // ---- dadj into regs; thread owns n0=2t, n1=2t+1
    float tl[16];
    #pragma unroll
    for (int e = 0; e < 16; ++e) tl[e] = teb[bt*16 + e];
    float dj0[16], dj1[16];
    #pragma unroll
    for (int h = 0; h < 16; ++h){
        float a0 = 0.f, a1 = 0.f;
        #pragma unroll
        for (int e = 0; e < 16; ++e){
            float2 av = *(const float2*)(adj + ((e*16 + h) << 10) + 2*t);
            a0 += tl[e]*av.x; a1 += tl[e]*av.y;
        }
        dj0[h] = a0; dj1[h] = a1;
    }

    // ---- P build: wave w -> rows [128w, 128w+128), batches of 8 rows
    {
        unsigned int* xst = XST + w*256;
        const float* xb = x + (size_t)bt * 65536;
        int half = l >> 5, j32 = l & 31;
        for (int bi = 0; bi < 16; ++bi){
            int r0 = w*128 + bi*8;
            #pragma unroll
            for (int rr = 0; rr < 8; rr += 2){
                int row = r0 + rr + half;
                float2 xv = *(const float2*)(xb + row*64 + 2*j32);
                xst[(rr + half)*32 + j32] = pkrtz(xv.x, xv.y);
            }
            unsigned int pk4[4];
            #pragma unroll
            for (int pp = 0; pp < 4; ++pp){
                float ya0 = 0.f, ya1 = 0.f, yb0 = 0.f, yb1 = 0.f;
                #pragma unroll
                for (int jq = 0; jq < 8; ++jq){
                    uint4 xa = *(uint4*)&xst[(2*pp)*32 + 4*jq];
                    uint4 xbq = *(uint4*)&xst[(2*pp+1)*32 + 4*jq];
                    ya0 = fdot2u(xa.x,  wpk[4*jq+0], ya0);
                    ya1 = fdot2u(xa.y,  wpk[4*jq+1], ya1);
                    ya0 = fdot2u(xa.z,  wpk[4*jq+2], ya0);
                    ya1 = fdot2u(xa.w,  wpk[4*jq+3], ya1);
                    yb0 = fdot2u(xbq.x, wpk[4*jq+0], yb0);
                    yb1 = fdot2u(xbq.y, wpk[4*jq+1], yb1);
                    yb0 = fdot2u(xbq.z, wpk[4*jq+2], yb0);
                    yb1 = fdot2u(xbq.w, wpk[4*jq+3], yb1);
                }
                float ya = bpd + ya0 + ya1;
                float yb = bpd + yb0 + yb1;
                float sna = wredsum64(ya*ya);
                float snb = wredsum64(yb*yb);
                pk4[pp] = pkrtz(ya*squash_sc(sna), yb*squash_sc(snb));
            }
            *(uint4*)&PT[ptq_idx(l, w*16 + bi)] = make_uint4(pk4[0], pk4[1], pk4[2], pk4[3]);
        }
    }
    __syncthreads();

    float bb0[16], bb1[16];
    #pragma unroll
    for (int h = 0; h < 16; ++h){ bb0[h] = 0.f; bb1[h] = 0.f; }
    float v1a = 0.f, v1b = 0.f;

    const int o = w & 1, G = w >> 1;   // h-oct, m-quarter

    #pragma unroll 1
    for (int pass = 0; pass < 5; ++pass){
        // --- per-thread softmax over h (for n0 and n1)
        float c0[16], c1[16];
        {
            float sv0[16], sv1[16];
            #pragma unroll
            for (int h = 0; h < 16; ++h){
                if (pass == 0){ sv0[h] = dj0[h]; sv1[h] = dj1[h]; }
                else if (pass < 4){ sv0[h] = bb0[h]; sv1[h] = bb1[h]; }
                else { sv0[h] = bb0[h] + dj0[h]; sv1[h] = bb1[h] + dj1[h]; }
            }
            float M0 = sv0[0], M1 = sv1[0];
            #pragma unroll
            for (int h = 1; h < 16; ++h){ M0 = fmaxf(M0, sv0[h]); M1 = fmaxf(M1, sv1[h]); }
            float S0 = 0.f, S1 = 0.f;
            #pragma unroll
            for (int h = 0; h < 16; ++h){
                c0[h] = __expf(sv0[h] - M0); S0 += c0[h];
                c1[h] = __expf(sv1[h] - M1); S1 += c1[h];
            }
            float i0 = 1.f/S0, i1 = 1.f/S1;
            #pragma unroll
            for (int h = 0; h < 16; ++h){ c0[h] *= i0; c1[h] *= i1; }
            if (pass == 4){
                #pragma unroll
                for (int h = 0; h < 16; ++h){
                    float2 cw; cw.x = c0[h]; cw.y = c1[h];
                    *(float2*)(cout + ((size_t)bt*16 + h)*1024 + 2*t) = cw;
                }
            }
        }

        // --- contraction t[h][d] = sum_n c[h][n] * P[n][d]
        float acc[8];
        #pragma unroll
        for (int hh = 0; hh < 8; ++hh) acc[hh] = 0.f;

        #pragma unroll
        for (int ch = 0; ch < 2; ++ch){
            __syncthreads();
            if ((t >> 8) == ch){
                int mc = t & 255;
                #pragma unroll
                for (int h = 0; h < 16; ++h) CL[h*256 + mc] = pkrtz(c0[h], c1[h]);
            }
            __syncthreads();
            #pragma unroll
            for (int q = 0; q < 16; ++q){
                int mcq = G*16 + q;
                int mb  = ch*64 + mcq;
                uint4 pt = *(uint4*)&PT[ptq_idx(l, mb)];
                #pragma unroll
                for (int hh = 0; hh < 8; ++hh){
                    uint4 cq = *(uint4*)&CL[(8*o + hh)*256 + 4*mcq];
                    acc[hh] = fdot2u(cq.x, pt.x, acc[hh]);
                    acc[hh] = fdot2u(cq.y, pt.y, acc[hh]);
                    acc[hh] = fdot2u(cq.z, pt.z, acc[hh]);
                    acc[hh] = fdot2u(cq.w, pt.w, acc[hh]);
                }
            }
        }
        __syncthreads();
        #pragma unroll
        for (int hh = 0; hh < 8; ++hh) TP[(G*16 + 8*o + hh)*68 + l] = acc[hh];
        __syncthreads();

        // --- owner wave w handles h = 2w, 2w+1 (lane = d)
        {
            float t0 = 0.f, t1 = 0.f;
            #pragma unroll
            for (int g2 = 0; g2 < 4; ++g2){
                t0 += TP[(g2*16 + 2*w    )*68 + l];
                t1 += TP[(g2*16 + 2*w + 1)*68 + l];
            }
            if (pass == 0){
                float sn0 = wredsum64(t0*t0), sn1 = wredsum64(t1*t1);
                v1a = t0*squash_sc(sn0); v1b = t1*squash_sc(sn1);
            } else if (pass < 4){
                float q0 = v1a*t0, q1 = v1b*t1;
                float sn0 = wredsum64(q0*q0), sn1 = wredsum64(q1*q1);
                VB[(2*w    )*68 + l] = q0*squash_sc(sn0);
                VB[(2*w + 1)*68 + l] = q1*squash_sc(sn1);
            } else {
                sbuf[((size_t)bt*16 + 2*w    )*64 + l] = t0;
                sbuf[((size_t)bt*16 + 2*w + 1)*64 + l] = t1;
            }
        }

        if (pass >= 1 && pass <= 3){
            __syncthreads();   // VB ready
            // bupd: thread owns m=t (rows n0=2t, n1=2t+1)
            int mb = t >> 2, off = t & 3;
            #pragma unroll
            for (int dq = 0; dq < 16; ++dq){
                float p0[4], p1[4];
                #pragma unroll
                for (int i = 0; i < 4; ++i){
                    int d = dq*4 + i;
                    unsigned int pv = PT[ptq_idx(d, mb) + off];
                    p0[i] = loF(pv); p1[i] = hiF(pv);
                }
                #pragma unroll
                for (int h = 0; h < 16; ++h){
                    float4 vb4 = *(float4*)&VB[h*68 + dq*4];
                    bb0[h] += vb4.x*p0[0] + vb4.y*p0[1] + vb4.z*p0[2] + vb4.w*p0[3];
                    bb1[h] += vb4.x*p1[0] + vb4.y*p1[1] + vb4.z*p1[2] + vb4.w*p1[3];
                }
            }
        }
    }
}

// dyn[b,h,k] = sum_e time_eb[b,e]*t_adj[e,h,k]
__global__ __launch_bounds__(192) void k_dyn(const float* __restrict__ timeb,
        const float* __restrict__ tadj, float* __restrict__ dyn){
    int b = blockIdx.x, h = blockIdx.y, k = threadIdx.x;
    float acc = 0.f;
    #pragma unroll
    for (int e = 0; e < 16; ++e)
        acc += timeb[b*16+e]*tadj[((size_t)e*HT_+h)*TT_ + k];
    dyn[((size_t)b*HT_+h)*TT_ + k] = acc;
}

// tem[b,h,d] = lrelu( sum_k dyn[b,h,k]*(s[b,k,d] + mask[k>>4]) )  grid (16,16) x 256
__global__ __launch_bounds__(256) void k_tem(const float* __restrict__ dyn,
        const float* __restrict__ sbuf, float* __restrict__ tem){
    int b = blockIdx.x, hg = blockIdx.y;
    int w = threadIdx.x >> 6, l = threadIdx.x & 63;
    int h = hg*4 + w;
    const float* dr = dyn + ((size_t)b*HT_ + h)*TT_;
    const float* sb = sbuf + (size_t)b*TT_*64;
    float a0 = 0.f, a1 = 0.f;
    #pragma unroll 4
    for (int k = 0; k < TT_; k += 2){
        float m0 = (float)((k>>4)+1) * (1.f/12.f);
        float m1 = (float)(((k+1)>>4)+1) * (1.f/12.f);
        a0 += dr[k]   * (sb[(size_t)k*64 + l]     + m0);
        a1 += dr[k+1] * (sb[(size_t)(k+1)*64 + l] + m1);
    }
    float a = a0 + a1;
    tem[((size_t)b*HT_ + h)*64 + l] = lrelu_(a);
}

// ret=lrelu(sum_h dyn*tem)+s; v2=squash(ret)   grid (16,48) x 256
__global__ __launch_bounds__(256) void k_retv2(const float* __restrict__ dyn,
        const float* __restrict__ temb, const float* __restrict__ sbuf,
        float* __restrict__ v2){
    int b = blockIdx.x, kg = blockIdx.y;
    int w = threadIdx.x >> 6, l = threadIdx.x & 63;
    int k = kg*4 + w;
    const float* tb = temb + (size_t)b*HT_*64;
    float a0 = 0.f, a1 = 0.f;
    #pragma unroll 4
    for (int h = 0; h < HT_; h += 2){
        a0 += dyn[((size_t)b*HT_ + h  )*TT_ + k] * tb[(size_t)h*64 + l];
        a1 += dyn[((size_t)b*HT_ + h+1)*TT_ + k] * tb[(size_t)(h+1)*64 + l];
    }
    float a = lrelu_(a0 + a1);
    float r = a + sbuf[((size_t)b*TT_ + k)*64 + l];
    float sn = wredsum64(r*r);
    v2[((size_t)b*TT_ + k)*64 + l] = r*squash_sc(sn);
}

// recon (f16 packed pairs): rec[bt,n,d] = sum_h c[bt,h,n]*v2[bt,h,d]  grid (192,8) x 256
__global__ __launch_bounds__(256) void k_rec(const float* __restrict__ cbuf,
        const float* __restrict__ v2, unsigned int* __restrict__ recpk){
    __shared__ float vL[16*68];
    __shared__ float cL[16*132];
    int bt = blockIdx.x, nc = blockIdx.y;
    int t = threadIdx.x, l = t & 63, g = t >> 6;
    #pragma unroll
    for (int i = 0; i < 4; ++i){
        int idx = i*256 + t;
        vL[(idx>>6)*68 + (idx&63)] = v2[(size_t)bt*1024 + idx];
    }
    #pragma unroll
    for (int i = 0; i < 8; ++i){
        int idx = i*256 + t;   // h = idx>>7, j = idx&127
        cL[(idx>>7)*132 + (idx&127)] =
            cbuf[((size_t)bt*16 + (idx>>7))*1024 + nc*128 + (idx&127)];
    }
    __syncthreads();
    float vreg[16];
    #pragma unroll
    for (int h = 0; h < 16; ++h) vreg[h] = vL[h*68 + l];
    #pragma unroll 4
    for (int i = 0; i < 32; ++i){
        int nl = g + 4*i;
        float a = 0.f;
        #pragma unroll
        for (int h = 0; h < 16; ++h) a += cL[h*132 + nl]*vreg[h];
        float ap = __shfl_xor(a, 1, 64);
        if (!(l & 1))
            recpk[((size_t)bt*1024 + nc*128 + nl)*32 + (l>>1)] = pkrtz(a, ap);
    }
}

// out = lrelu(rec @ wsp[n] + bsp[n] + x)   grid 1024 x 256
__global__ __launch_bounds__(256) void k_final(const float* __restrict__ x,
        const float* __restrict__ ne, const float* __restrict__ wspa,
        const float* __restrict__ bspa, const unsigned int* __restrict__ recpk,
        float* __restrict__ out){
    __shared__ float wspL[64*68];
    __shared__ float bspL[64];
    int n = blockIdx.x, t = threadIdx.x, l = t & 63, g = t >> 6;
    float nl16[16];
    #pragma unroll
    for (int e = 0; e < 16; ++e) nl16[e] = ne[n*16 + e];
    #pragma unroll
    for (int j = 0; j < 16; ++j){
        int io = j*256 + t;
        float a = 0.f;
        #pragma unroll
        for (int e = 0; e < 16; ++e) a += nl16[e]*wspa[(size_t)e*4096 + io];
        wspL[(io>>6)*68 + (io&63)] = a;
    }
    if (t < 64){
        float a = 0.f;
        #pragma unroll
        for (int e = 0; e < 16; ++e) a += nl16[e]*bspa[e*64 + t];
        bspL[t] = a;
    }
    __syncthreads();
    unsigned int wr[32];
    #pragma unroll
    for (int ip = 0; ip < 32; ++ip)
        wr[ip] = pkrtz(wspL[(2*ip)*68 + l], wspL[(2*ip+1)*68 + l]);
    float bsp = bspL[l];
    #pragma unroll 2
    for (int i = 0; i < 48; ++i){
        int bt = g + 4*i;
        const uint4* rp = (const uint4*)(recpk + ((size_t)bt*1024 + n)*32);
        float o0 = bsp, o1 = 0.f;
        #pragma unroll
        for (int jj = 0; jj < 8; ++jj){
            uint4 rq = rp[jj];
            o0 = fdot2u(rq.x, wr[4*jj+0], o0);
            o1 = fdot2u(rq.y, wr[4*jj+1], o1);
            o0 = fdot2u(rq.z, wr[4*jj+2], o0);
            o1 = fdot2u(rq.w, wr[4*jj+3], o1);
        }
        size_t oidx = ((size_t)bt*1024 + n)*64 + l;
        float r = o0 + o1 + x[oidx];
        out[oidx] = lrelu_(r);
    }
}

extern "C" void kernel_launch(void* const* d_in, const int* in_sizes, int n_in,
                              void* d_out, int out_size, void* d_ws, size_t ws_size,
                              hipStream_t stream) {
    const float* x     = (const float*)d_in[0];
    const float* ne    = (const float*)d_in[1];
    const float* timeb = (const float*)d_in[2];
    const float* teb   = (const float*)d_in[3];
    const float* Wp    = (const float*)d_in[4];
    const float* bp    = (const float*)d_in[5];
    const float* tadj  = (const float*)d_in[6];
    const float* adj   = (const float*)d_in[7];
    const float* wspa  = (const float*)d_in[8];
    const float* bspa  = (const float*)d_in[9];

    float* out    = (float*)d_out;
    float* outc   = out  + (size_t)BT_*N_*64;      // c:   [BT,HS,N]
    float* outdyn = outc + (size_t)BT_*HS_*N_;     // dyn: [B,HT,TT]

    float* ws   = (float*)d_ws;
    float* sbuf = ws;                               // [BT,16,64]
    float* temb = sbuf + (size_t)BT_*HS_*64;        // [B,64,64]
    float* v2   = temb + (size_t)B_*HT_*64;         // [BT,16,64]
    unsigned int* recpk = (unsigned int*)(v2 + (size_t)BT_*HS_*64); // [BT,1024,32] u32

    (void)hipFuncSetAttribute((const void*)k_mega,
            hipFuncAttributeMaxDynamicSharedMemorySize, MEGA_LDS);

    k_mega<<<dim3(BT_), 512, MEGA_LDS, stream>>>(x, Wp, bp, teb, adj, outc, sbuf);
    k_dyn<<<dim3(B_, HT_), 192, 0, stream>>>(timeb, tadj, outdyn);
    k_tem<<<dim3(B_, 16), 256, 0, stream>>>(outdyn, sbuf, temb);
    k_retv2<<<dim3(B_, 48), 256, 0, stream>>>(outdyn, temb, sbuf, v2);
    k_rec<<<dim3(BT_, 8), 256, 0, stream>>>(outc, v2, recpk);
    k_final<<<dim3(N_), 256, 0, stream>>>(x, ne, wspa, bspa, recpk, out);
}